// Round 7
// baseline (401.092 us; speedup 1.0000x reference)
//
#include <hip/hip_runtime.h>
#include <cstdint>
#include <cstddef>

using u16 = unsigned short;
using u32 = uint32_t;

typedef __attribute__((ext_vector_type(8))) short short8;
typedef __attribute__((ext_vector_type(4))) float floatx4;

#define DEVFN static __device__ __forceinline__

// 0.125 * log2(e): fold attention scale into q, softmax runs in log2 domain
#define QSCALE 0.18033688011112042f

DEVFN u16 f2bf(float f) {
  u32 u = __float_as_uint(f);
  return (u16)((u + 0x7fffu + ((u >> 16) & 1u)) >> 16);
}

DEVFN float b2f(u16 u) { return __uint_as_float(((u32)u) << 16); }

DEVFN void async_load16(const void* g, const void* lds) {
  __builtin_amdgcn_global_load_lds(
      (const __attribute__((address_space(1))) u32*)(uintptr_t)g,
      (__attribute__((address_space(3))) u32*)(u32)(uintptr_t)lds,
      16, 0, 0);
}

DEVFN void cvt4(const float* __restrict__ src, u16* __restrict__ dst, int i) {
  const float4 v = ((const float4*)src)[i];
  ushort4 o;
  o.x = f2bf(v.x); o.y = f2bf(v.y); o.z = f2bf(v.z); o.w = f2bf(v.w);
  ((ushort4*)dst)[i] = o;
}

// ---------------- fused prep: rope tables + all weight cvts + LN1 ----------------
// grid ranges: [0,256) rope | [256,3328) Wqkv | [3328,4352) Wo |
//              [4352,9600) Wi-permute | [9600,12224) Wmlp | [12224,16320) LN1
__global__ __launch_bounds__(256)
void prep_k(const float* __restrict__ Wqkv, const float* __restrict__ Wo,
            const float* __restrict__ Wi, const float* __restrict__ Wmlp,
            const float* __restrict__ hidden, const float* __restrict__ ln1g,
            const float* __restrict__ ln1b,
            u16* __restrict__ wqkv_bf, u16* __restrict__ wo_bf,
            u16* __restrict__ wi_bf, u16* __restrict__ wmlp_bf,
            float* __restrict__ ct, float* __restrict__ st, u16* __restrict__ xn) {
  const int bid = blockIdx.x;
  const int tid = threadIdx.x;
  __shared__ float red[8];
  if (bid < 256) {
    const int i = bid * 256 + tid;
    const int m = i >> 5, f = i & 31;
    const float inv = exp2f((float)f * -0.41524101186092025f);  // 10000^(-f/32)
    const float ang = (float)m * inv;
    ct[i] = cosf(ang);
    st[i] = sinf(ang);
  } else if (bid < 3328) {
    cvt4(Wqkv, wqkv_bf, (bid - 256) * 256 + tid);
  } else if (bid < 4352) {
    cvt4(Wo, wo_bf, (bid - 3328) * 256 + tid);
  } else if (bid < 9600) {
    // Wi permute: dst row p=g*32+c: c<16 -> Wi row g*16+c, else 2624+g*16+(c-16)
    const int i = (bid - 4352) * 256 + tid;
    const int i4 = i * 4;
    const int p = i4 >> 10, kc = i4 & 1023;
    const int g = p >> 5, c = p & 31;
    const int srow = (c < 16) ? (g * 16 + c) : (2624 + g * 16 + (c - 16));
    const float4 v = *(const float4*)(Wi + (size_t)srow * 1024 + kc);
    ushort4 o;
    o.x = f2bf(v.x); o.y = f2bf(v.y); o.z = f2bf(v.z); o.w = f2bf(v.w);
    ((ushort4*)wi_bf)[i] = o;
  } else if (bid < 12224) {
    cvt4(Wmlp, wmlp_bf, (bid - 9600) * 256 + tid);
  } else {
    const int row = bid - 12224;
    const float4 v = ((const float4*)(hidden + (size_t)row * 1024))[tid];
    float s = v.x + v.y + v.z + v.w;
    float ss = v.x * v.x + v.y * v.y + v.z * v.z + v.w * v.w;
#pragma unroll
    for (int d = 32; d > 0; d >>= 1) {
      s += __shfl_xor(s, d);
      ss += __shfl_xor(ss, d);
    }
    const int wave = tid >> 6;
    if ((tid & 63) == 0) { red[wave] = s; red[4 + wave] = ss; }
    __syncthreads();
    s = red[0] + red[1] + red[2] + red[3];
    ss = red[4] + red[5] + red[6] + red[7];
    const float mu = s * (1.f / 1024.f);
    const float var = ss * (1.f / 1024.f) - mu * mu;
    const float rr = rsqrtf(var + 1e-5f);
    const float4 gv = ((const float4*)ln1g)[tid];
    const float4 bv = ((const float4*)ln1b)[tid];
    u16* orow = xn + (size_t)row * 1024 + tid * 4;
    orow[0] = f2bf((v.x - mu) * rr * gv.x + bv.x);
    orow[1] = f2bf((v.y - mu) * rr * gv.y + bv.y);
    orow[2] = f2bf((v.z - mu) * rr * gv.z + bv.z);
    orow[3] = f2bf((v.w - mu) * rr * gv.w + bv.w);
  }
}

// ---------------- reduce 3 partials + residual + layernorm ----------------
__global__ __launch_bounds__(256)
void red_ln_k(const float* __restrict__ resid, const u16* __restrict__ p0,
              const u16* __restrict__ p1, const u16* __restrict__ p2,
              const float* __restrict__ g, const float* __restrict__ bb,
              float* __restrict__ outx, u16* __restrict__ outn) {
  const int row = blockIdx.x;
  const int tid = threadIdx.x;
  const size_t base = (size_t)row * 1024;
  const float4 h = ((const float4*)(resid + base))[tid];
  const ushort4 a = ((const ushort4*)(p0 + base))[tid];
  const ushort4 c = ((const ushort4*)(p1 + base))[tid];
  const ushort4 d = ((const ushort4*)(p2 + base))[tid];
  float4 v;
  v.x = h.x + b2f(a.x) + b2f(c.x) + b2f(d.x);
  v.y = h.y + b2f(a.y) + b2f(c.y) + b2f(d.y);
  v.z = h.z + b2f(a.z) + b2f(c.z) + b2f(d.z);
  v.w = h.w + b2f(a.w) + b2f(c.w) + b2f(d.w);
  float s = v.x + v.y + v.z + v.w;
  float ss = v.x * v.x + v.y * v.y + v.z * v.z + v.w * v.w;
#pragma unroll
  for (int dd = 32; dd > 0; dd >>= 1) {
    s += __shfl_xor(s, dd);
    ss += __shfl_xor(ss, dd);
  }
  __shared__ float red[8];
  const int wave = tid >> 6;
  if ((tid & 63) == 0) { red[wave] = s; red[4 + wave] = ss; }
  __syncthreads();
  s = red[0] + red[1] + red[2] + red[3];
  ss = red[4] + red[5] + red[6] + red[7];
  const float mu = s * (1.f / 1024.f);
  const float var = ss * (1.f / 1024.f) - mu * mu;
  const float rr = rsqrtf(var + 1e-5f);
  ((float4*)(outx + base))[tid] = v;
  const float4 gv = ((const float4*)g)[tid];
  const float4 bv = ((const float4*)bb)[tid];
  u16* orow = outn + base + tid * 4;
  orow[0] = f2bf((v.x - mu) * rr * gv.x + bv.x);
  orow[1] = f2bf((v.y - mu) * rr * gv.y + bv.y);
  orow[2] = f2bf((v.z - mu) * rr * gv.z + bv.z);
  orow[3] = f2bf((v.w - mu) * rr * gv.w + bv.w);
}

// ---------------- final: out += p0+p1+p2+p3 ----------------
__global__ void red_add_k(float* __restrict__ out, const u16* __restrict__ p0,
                          const u16* __restrict__ p1, const u16* __restrict__ p2,
                          const u16* __restrict__ p3) {
  const int i = blockIdx.x * 256 + threadIdx.x;  // 1048576
  float4 v = ((const float4*)out)[i];
  const ushort4 a = ((const ushort4*)p0)[i];
  const ushort4 c = ((const ushort4*)p1)[i];
  const ushort4 d = ((const ushort4*)p2)[i];
  const ushort4 e = ((const ushort4*)p3)[i];
  v.x += b2f(a.x) + b2f(c.x) + b2f(d.x) + b2f(e.x);
  v.y += b2f(a.y) + b2f(c.y) + b2f(d.y) + b2f(e.y);
  v.z += b2f(a.z) + b2f(c.z) + b2f(d.z) + b2f(e.z);
  v.w += b2f(a.w) + b2f(c.w) + b2f(d.w) + b2f(e.w);
  ((float4*)out)[i] = v;
}

// ---------------- attention split combine: att = (po0+po1)/(li0+li1) ----------------
// In-place safe over po1 (same element index). Layout [row 4096][1024].
__global__ void attn_red_k(const u16* __restrict__ po0, const u16* __restrict__ po1,
                           const float* __restrict__ lig, u16* __restrict__ att) {
  const int i = blockIdx.x * 256 + threadIdx.x;  // 1048576 ushort4 groups
  const int c4 = i & 255, row = i >> 8;
  const int h = c4 >> 4, b = row >> 11, m = row & 2047;
  const int liidx = (b * 16 + h) * 2048 + m;
  const float rl = 1.f / (lig[liidx] + lig[65536 + liidx]);
  const ushort4 a = ((const ushort4*)po0)[i];
  const ushort4 c = ((const ushort4*)po1)[i];
  ushort4 o;
  o.x = f2bf((b2f(a.x) + b2f(c.x)) * rl);
  o.y = f2bf((b2f(a.y) + b2f(c.y)) * rl);
  o.z = f2bf((b2f(a.z) + b2f(c.z)) * rl);
  o.w = f2bf((b2f(a.w) + b2f(c.w)) * rl);
  ((ushort4*)att)[i] = o;
}

// XCD-rectangle swizzle: linear dispatch p -> (tn, tm). Round-robin XCD
// assignment (p%8) gets a contiguous logical range; GROUP_M=8 banding makes
// the ~32 concurrent blocks per XCD an 8m x 4n rectangle (~3MB, fits 4MB L2).
DEVFN void swizzle_tile(int NT, int& tn, int& tm) {
  const int tpx = gridDim.x >> 3;
  const int p = blockIdx.x;
  const int lid = (p & 7) * tpx + (p >> 3);
  const int band = lid / (8 * NT);
  const int rem = lid - band * 8 * NT;
  tn = (rem >> 3) * 128;
  tm = (band * 8 + (rem & 7)) * 128;
}

// ---------------- GEMM: C = A @ B^T, 128x128 tile, BK=32 ----------------
struct EpiArgs {
  const float* bias;
  u16* q; u16* kk; u16* vt;
  u16* outbf;
  const float* ct; const float* st;
};

// EPI 0: QKV (bias + rope + scatter to q/k/vt; q pre-scaled; vt key-permuted)
// EPI 2: gelu-gate -> outbf (act, width 2624)
template <int EPI>
__global__ __launch_bounds__(256, 3)
void gemm_k(const u16* __restrict__ A, const u16* __restrict__ B, int K, int NT,
            EpiArgs ea) {
  __shared__ __align__(16) u16 sA[128 * 32];
  __shared__ __align__(16) u16 sB[128 * 32];
  int tn, tm;
  swizzle_tile(NT, tn, tm);
  const int tid = threadIdx.x;
  const int wave = tid >> 6, lane = tid & 63;
  const int quad = lane >> 4, l15 = lane & 15;
  const int wm = (wave >> 1) * 64, wn = (wave & 1) * 64;

  floatx4 acc[4][4];
#pragma unroll
  for (int i = 0; i < 4; ++i)
#pragma unroll
    for (int j = 0; j < 4; ++j) acc[i][j] = (floatx4){0.f, 0.f, 0.f, 0.f};

  const int srow = lane >> 2;
  const int skc = (lane & 3) * 8;
  const u16* sAr = sA + (wm + l15) * 32 + quad * 8;
  const u16* sBr = sB + (wn + l15) * 32 + quad * 8;

  for (int k0 = 0; k0 < K; k0 += 32) {
#pragma unroll
    for (int j = 0; j < 2; ++j) {
      const int q = wave * 2 + j;
      const int row = q * 16 + srow;
      async_load16(A + (size_t)(tm + row) * K + (k0 + skc), (const char*)sA + q * 1024);
      async_load16(B + (size_t)(tn + row) * K + (k0 + skc), (const char*)sB + q * 1024);
    }
    __syncthreads();
    short8 af[4], bfr[4];
#pragma unroll
    for (int t = 0; t < 4; ++t) af[t] = *(const short8*)(sAr + t * 512);
#pragma unroll
    for (int t = 0; t < 4; ++t) bfr[t] = *(const short8*)(sBr + t * 512);
#pragma unroll
    for (int ti = 0; ti < 4; ++ti)
#pragma unroll
      for (int tj = 0; tj < 4; ++tj)
        acc[ti][tj] = __builtin_amdgcn_mfma_f32_16x16x32_bf16(af[ti], bfr[tj], acc[ti][tj], 0, 0, 0);
    __syncthreads();
  }

  if constexpr (EPI == 0) {
    const int col0 = tn + wn;            // multiple of 64 -> one head per wave
    const int t = col0 >> 10;            // 0=q 1=k 2=v
    const int h = (col0 & 1023) >> 6;
    if (t == 2) {
      // vt with key-permuted token positions: key m -> pos (m&~31)|((m&15)*2)|((m>>4)&1)
#pragma unroll
      for (int ti = 0; ti < 4; ++ti)
#pragma unroll
        for (int r = 0; r < 4; ++r) {
          const int row = tm + wm + ti * 16 + quad * 4 + r;
          const int b = row >> 11, m = row & 2047;
          const int mp = (m & ~31) | ((m & 15) << 1) | ((m >> 4) & 1);
#pragma unroll
          for (int tj = 0; tj < 4; ++tj) {
            const int dh = tj * 16 + l15;
            const float v = acc[ti][tj][r] + ea.bias[col0 + dh];
            ea.vt[((size_t)((b * 16 + h) * 64 + dh)) * 2048 + mp] = f2bf(v);
          }
        }
    } else {
      u16* dst = (t == 0) ? ea.q : ea.kk;
      const float qs = (t == 0) ? QSCALE : 1.f;
#pragma unroll
      for (int ti = 0; ti < 4; ++ti)
#pragma unroll
        for (int r = 0; r < 4; ++r) {
          const int row = tm + wm + ti * 16 + quad * 4 + r;
          const int b = row >> 11, m = row & 2047;
          u16* drow = dst + ((size_t)(b * 16 + h) * 2048 + m) * 64;
#pragma unroll
          for (int tj = 0; tj < 2; ++tj) {
            const int i = tj * 16 + l15;                 // freq index 0..31
            const float x1 = acc[ti][tj][r] + ea.bias[col0 + i];
            const float x2 = acc[ti][tj + 2][r] + ea.bias[col0 + 32 + i];
            const float cs = ea.ct[m * 32 + i];
            const float sn = ea.st[m * 32 + i];
            drow[i] = f2bf((x1 * cs - x2 * sn) * qs);
            drow[32 + i] = f2bf((x1 * sn + x2 * cs) * qs);
          }
        }
    }
  } else {
#pragma unroll
    for (int ti = 0; ti < 4; ++ti)
#pragma unroll
      for (int r = 0; r < 4; ++r) {
        const int row = tm + wm + ti * 16 + quad * 4 + r;
#pragma unroll
        for (int u = 0; u < 2; ++u) {
          const float hin = acc[ti][2 * u][r];
          const float hg = acc[ti][2 * u + 1][r];
          const int a = (((tn + wn) >> 5) + u) * 16 + l15;
          // gelu(h) ~= h * sigmoid(2t), t = 0.7978845608(h + 0.044715 h^3)
          const float t2 = hin + 0.044715f * hin * hin * hin;
          const float e = __builtin_amdgcn_exp2f(t2 * -2.302114768f);  // -2*0.79788*log2e
          const float gl = hin * __builtin_amdgcn_rcpf(1.f + e);
          ea.outbf[(size_t)row * 2624 + a] = f2bf(gl * hg);
        }
      }
  }
}

// ---------------- split-K GEMM: 128x128 tile, bf16 partials ----------------
// z < zsw: kofs=z*kps1, kps=kps1; else kofs=zsw*kps1+(z-zsw)*kps2, kps=kps2
__global__ __launch_bounds__(256, 3)
void gemm_sk4(const u16* __restrict__ A, const u16* __restrict__ B, int K, int NT,
              int kps1, int zsw, int kps2,
              u16* __restrict__ p0, u16* __restrict__ p1,
              u16* __restrict__ p2, u16* __restrict__ p3) {
  __shared__ __align__(16) u16 sA[128 * 32];
  __shared__ __align__(16) u16 sB[128 * 32];
  int tn, tm;
  swizzle_tile(NT, tn, tm);
  const int z = blockIdx.y;
  int kofs, kps;
  if (z < zsw) { kofs = z * kps1; kps = kps1; }
  else { kofs = zsw * kps1 + (z - zsw) * kps2; kps = kps2; }
  const int tid = threadIdx.x;
  const int wave = tid >> 6, lane = tid & 63;
  const int quad = lane >> 4, l15 = lane & 15;
  const int wm = (wave >> 1) * 64, wn = (wave & 1) * 64;

  floatx4 acc[4][4];
#pragma unroll
  for (int i = 0; i < 4; ++i)
#pragma unroll
    for (int j = 0; j < 4; ++j) acc[i][j] = (floatx4){0.f, 0.f, 0.f, 0.f};

  const int srow = lane >> 2;
  const int skc = (lane & 3) * 8;
  const u16* sAr = sA + (wm + l15) * 32 + quad * 8;
  const u16* sBr = sB + (wn + l15) * 32 + quad * 8;

  for (int k0 = 0; k0 < kps; k0 += 32) {
    const int kk = kofs + k0;
#pragma unroll
    for (int j = 0; j < 2; ++j) {
      const int q = wave * 2 + j;
      const int row = q * 16 + srow;
      async_load16(A + (size_t)(tm + row) * K + (kk + skc), (const char*)sA + q * 1024);
      async_load16(B + (size_t)(tn + row) * K + (kk + skc), (const char*)sB + q * 1024);
    }
    __syncthreads();
    short8 af[4], bfr[4];
#pragma unroll
    for (int t = 0; t < 4; ++t) af[t] = *(const short8*)(sAr + t * 512);
#pragma unroll
    for (int t = 0; t < 4; ++t) bfr[t] = *(const short8*)(sBr + t * 512);
#pragma unroll
    for (int ti = 0; ti < 4; ++ti)
#pragma unroll
      for (int tj = 0; tj < 4; ++tj)
        acc[ti][tj] = __builtin_amdgcn_mfma_f32_16x16x32_bf16(af[ti], bfr[tj], acc[ti][tj], 0, 0, 0);
    __syncthreads();
  }

  u16* part = (z == 0) ? p0 : (z == 1) ? p1 : (z == 2) ? p2 : p3;
#pragma unroll
  for (int ti = 0; ti < 4; ++ti)
#pragma unroll
    for (int r = 0; r < 4; ++r) {
      const int row = tm + wm + ti * 16 + quad * 4 + r;
#pragma unroll
      for (int tj = 0; tj < 4; ++tj)
        part[(size_t)row * 1024 + tn + wn + tj * 16 + l15] = f2bf(acc[ti][tj][r]);
    }
}

// ---------------- flash attention, k-split ----------------
// grid (16 q-tiles of 128, 32 b*h, 2 k-splits); block 256 = 4 waves x 32 q-rows.
// Fixed-max log2-domain softmax is LINEAR over disjoint key ranges -> exact
// split-k: each block does 8 k-tiles, emits unnormalized bf16 o-partials +
// f32 li partials; attn_red_k combines. Chunked 32-key QK^T->softmax->PV keeps
// live score regs to 16 (was 64) and sP to one 5KB slot (two-phase per group):
// LDS 37KB + ~110 regs -> 4 blocks/CU (r6 was stuck at 2 waves/SIMD).
__global__ __launch_bounds__(256, 4)
void attn_k(const u16* __restrict__ qg, const u16* __restrict__ kg,
            const u16* __restrict__ vtg, const int* __restrict__ mask,
            u16* __restrict__ po0, u16* __restrict__ po1,
            float* __restrict__ lig) {
  __shared__ __align__(16) u16 sK[8 * 128 * 8];    // [chunk][key][8 u16] 16KB
  __shared__ __align__(16) u16 sV[16 * 64 * 8];    // [chunk][dh][8 u16] 16KB
  __shared__ __align__(16) u16 sP[4 * 16 * 40];    // [wave][16 rows][40] 5KB
  const int bh = blockIdx.y;
  const int b = bh >> 4, h = bh & 15;
  const int q0 = blockIdx.x * 128;
  const int z = blockIdx.z;
  const int tid = threadIdx.x;
  const int wave = tid >> 6, lane = tid & 63;
  const int quad = lane >> 4, l15 = lane & 15;
  const size_t bhk = (size_t)bh * 2048 * 64;
  const size_t bhv = (size_t)bh * 64 * 2048;

  short8 aq[2][2];
#pragma unroll
  for (int g = 0; g < 2; ++g) {
    const u16* qptr = qg + ((size_t)bh * 2048 + q0 + wave * 32 + g * 16 + l15) * 64 + quad * 8;
    aq[g][0] = *(const short8*)qptr;
    aq[g][1] = *(const short8*)(qptr + 32);
  }

  floatx4 o[2][4];
#pragma unroll
  for (int g = 0; g < 2; ++g)
#pragma unroll
    for (int t = 0; t < 4; ++t) o[g][t] = (floatx4){0.f, 0.f, 0.f, 0.f};
  float li[2][4] = {{0.f, 0.f, 0.f, 0.f}, {0.f, 0.f, 0.f, 0.f}};
  const floatx4 z4 = {0.f, 0.f, 0.f, 0.f};
  u32* pw32 = (u32*)sP + wave * 320;
  const u16* pr = sP + wave * 640 + l15 * 40 + quad * 8;

  for (int kt = 0; kt < 8; ++kt) {
    const int key0 = z * 1024 + kt * 128;
    // stage K (16KB) + V (16KB): 32 1KB issues, 8 per wave
#pragma unroll
    for (int j = 0; j < 8; ++j) {
      const int qi = wave * 8 + j;
      if (qi < 16) {
        const int chunk = qi >> 1, half = qi & 1;
        const int row = half * 64 + lane;
        async_load16(kg + bhk + (size_t)(key0 + row) * 64 + chunk * 8,
                     (const char*)sK + qi * 1024);
      } else {
        const int vi = qi - 16;
        const int c = vi >> 2, kc = vi & 3;
        async_load16(vtg + bhv + (size_t)lane * 2048 + key0 + c * 32 + kc * 8,
                     (const char*)sV + vi * 1024);
      }
    }
    float mb[8];
#pragma unroll
    for (int tj = 0; tj < 8; ++tj)
      mb[tj] = (mask[b * 2048 + key0 + tj * 16 + l15] > 0) ? 0.f : -1e30f;
    __syncthreads();

    // per 32-key chunk: QK^T -> softmax -> pack -> PV (live scores = 16 regs)
#pragma unroll
    for (int c = 0; c < 4; ++c) {
      floatx4 s[2][2];
#pragma unroll
      for (int t = 0; t < 2; ++t) {
        const int tj = c * 2 + t;
        const short8 b0 = *(const short8*)(sK + quad * 1024 + (tj * 16 + l15) * 8);
        const short8 b1 = *(const short8*)(sK + (4 + quad) * 1024 + (tj * 16 + l15) * 8);
        s[0][t] = __builtin_amdgcn_mfma_f32_16x16x32_bf16(aq[0][0], b0, z4, 0, 0, 0);
        s[0][t] = __builtin_amdgcn_mfma_f32_16x16x32_bf16(aq[0][1], b1, s[0][t], 0, 0, 0);
        s[1][t] = __builtin_amdgcn_mfma_f32_16x16x32_bf16(aq[1][0], b0, z4, 0, 0, 0);
        s[1][t] = __builtin_amdgcn_mfma_f32_16x16x32_bf16(aq[1][1], b1, s[1][t], 0, 0, 0);
      }
#pragma unroll
      for (int g = 0; g < 2; ++g)
#pragma unroll
        for (int t = 0; t < 2; ++t)
#pragma unroll
          for (int r = 0; r < 4; ++r) {
            const float p = __builtin_amdgcn_exp2f(s[g][t][r] + mb[c * 2 + t]);
            s[g][t][r] = p;
            li[g][r] += p;
          }
      // two-phase pack through the single per-wave sP slot
      short8 ap[2];
#pragma unroll
      for (int g = 0; g < 2; ++g) {
#pragma unroll
        for (int r = 0; r < 4; ++r) {
          const u32 lo = __float_as_uint(s[g][0][r]) + 0x8000u;
          const u32 hi = __float_as_uint(s[g][1][r]) + 0x8000u;
          pw32[(quad * 4 + r) * 20 + l15] = __builtin_amdgcn_perm(hi, lo, 0x07060302);
        }
        asm volatile("s_waitcnt lgkmcnt(0)" ::: "memory");
        ap[g] = *(const short8*)pr;
      }
#pragma unroll
      for (int tj2 = 0; tj2 < 4; ++tj2) {
        const short8 bv = *(const short8*)(sV + (c * 4 + quad) * 512 + (tj2 * 16 + l15) * 8);
        o[0][tj2] = __builtin_amdgcn_mfma_f32_16x16x32_bf16(ap[0], bv, o[0][tj2], 0, 0, 0);
        o[1][tj2] = __builtin_amdgcn_mfma_f32_16x16x32_bf16(ap[1], bv, o[1][tj2], 0, 0, 0);
      }
    }
    __syncthreads();
  }

  // li: reduce over the 16-lane l15 group, store per split (f32)
#pragma unroll
  for (int g = 0; g < 2; ++g)
#pragma unroll
    for (int r = 0; r < 4; ++r) {
      float s = li[g][r];
      s += __shfl_xor(s, 1);
      s += __shfl_xor(s, 2);
      s += __shfl_xor(s, 4);
      s += __shfl_xor(s, 8);
      if (l15 == 0)
        lig[z * 65536 + bh * 2048 + (q0 + wave * 32 + g * 16 + quad * 4 + r)] = s;
    }

  // unnormalized o partials, bf16, att layout
  u16* pod = z ? po1 : po0;
#pragma unroll
  for (int g = 0; g < 2; ++g)
#pragma unroll
    for (int tj = 0; tj < 4; ++tj)
#pragma unroll
      for (int r = 0; r < 4; ++r) {
        const int m = q0 + wave * 32 + g * 16 + quad * 4 + r;
        pod[((size_t)b * 2048 + m) * 1024 + h * 64 + tj * 16 + l15] = f2bf(o[g][tj][r]);
      }
}

// ---------------- host ----------------
// ws layout (bytes)
static const size_t OFF_WQKV = 0;                       // wqkv_bf -> li partials -> mlp partial3
static const size_t OFF_WO   = 6291456;                 // 1024*1024 bf16
static const size_t OFF_WI   = 8388608;                 // 5248*1024 bf16; -> mlp partial2
static const size_t OFF_WMLP = 19136512;                // 1024*2624 bf16
static const size_t OFF_XN   = 24510464;                // xn -> attn po0 -> xn2 -> mlp partial0
static const size_t OFF_Q    = 32899072;                // q -> Wo partial0 -> act[0:]
static const size_t OFF_K    = 41287680;                // k -> Wo partial1 -> act cont.
static const size_t OFF_VT   = 49676288;                // vt -> Wo partial2 -> act tail
static const size_t OFF_ATT  = 58064896;                // rope -> attn po1 -> att -> mlp partial1
static const size_t OFF_ROPE = OFF_ATT;
static const size_t WS_NEED  = 66453504;

extern "C" void kernel_launch(void* const* d_in, const int* in_sizes, int n_in,
                              void* d_out, int out_size, void* d_ws, size_t ws_size,
                              hipStream_t stream) {
  (void)in_sizes; (void)n_in; (void)out_size;
  if (ws_size < WS_NEED) return;

  const float* hidden = (const float*)d_in[0];
  const int*   mask   = (const int*)d_in[1];
  const float* ln1g   = (const float*)d_in[2];
  const float* ln1b   = (const float*)d_in[3];
  const float* Wqkv   = (const float*)d_in[4];
  const float* Wqkvb  = (const float*)d_in[5];
  const float* Wo     = (const float*)d_in[6];
  const float* ln2g   = (const float*)d_in[7];
  const float* ln2b   = (const float*)d_in[8];
  const float* Wi     = (const float*)d_in[9];
  const float* Wmlp   = (const float*)d_in[10];
  float* out = (float*)d_out;
  char* ws = (char*)d_ws;

  u16* wqkv_bf = (u16*)(ws + OFF_WQKV);
  u16* wo_bf   = (u16*)(ws + OFF_WO);
  u16* wi_bf   = (u16*)(ws + OFF_WI);
  u16* wmlp_bf = (u16*)(ws + OFF_WMLP);
  u16* xn      = (u16*)(ws + OFF_XN);
  u16* qb      = (u16*)(ws + OFF_Q);
  u16* kb      = (u16*)(ws + OFF_K);
  u16* vtb     = (u16*)(ws + OFF_VT);
  u16* att     = (u16*)(ws + OFF_ATT);
  u16* act     = (u16*)(ws + OFF_Q);                    // 21.5MB spans q/k/vt regions
  float* ct    = (float*)(ws + OFF_ROPE);
  float* st    = (float*)(ws + OFF_ROPE + 262144);
  u16* po0     = (u16*)(ws + OFF_XN);                   // attn partials (xn dead post-QKV)
  u16* po1     = (u16*)(ws + OFF_ATT);                  // (rope tables dead post-QKV)
  float* lig   = (float*)(ws + OFF_WQKV);               // (wqkv_bf dead post-QKV)
  u16* wp0     = (u16*)(ws + OFF_Q);                    // Wo partials (q/k/vt dead post-attn)
  u16* wp1     = (u16*)(ws + OFF_K);
  u16* wp2     = (u16*)(ws + OFF_VT);
  u16* mp0     = (u16*)(ws + OFF_XN);                   // xn dead after Wi gemm
  u16* mp1     = (u16*)(ws + OFF_ATT);                  // att dead after Wo gemm
  u16* mp2     = (u16*)(ws + OFF_WI);                   // wi_bf dead after Wi gemm
  u16* mp3     = (u16*)(ws + OFF_WQKV);                 // wqkv+li dead by mlp time

  prep_k<<<16320, 256, 0, stream>>>(Wqkv, Wo, Wi, Wmlp, hidden, ln1g, ln1b,
                                    wqkv_bf, wo_bf, wi_bf, wmlp_bf, ct, st, xn);

  EpiArgs e1 = {Wqkvb, qb, kb, vtb, nullptr, ct, st};
  gemm_k<0><<<768, 256, 0, stream>>>(xn, wqkv_bf, 1024, 24, e1);

  attn_k<<<dim3(16, 32, 2), 256, 0, stream>>>(qb, kb, vtb, mask, po0, po1, lig);
  attn_red_k<<<4096, 256, 0, stream>>>(po0, po1, lig, att);

  gemm_sk4<<<dim3(256, 3), 256, 0, stream>>>(att, wo_bf, 1024, 8, 352, 2, 320,
                                             wp0, wp1, wp2, wp2);
  red_ln_k<<<4096, 256, 0, stream>>>(hidden, wp0, wp1, wp2, ln2g, ln2b, out, xn);

  EpiArgs e3 = {nullptr, nullptr, nullptr, nullptr, act, nullptr, nullptr};
  gemm_k<2><<<1312, 256, 0, stream>>>(xn, wi_bf, 1024, 41, e3);

  gemm_sk4<<<dim3(256, 4), 256, 0, stream>>>(act, wmlp_bf, 2624, 8, 672, 2, 640,
                                             mp0, mp1, mp2, mp3);
  red_add_k<<<4096, 256, 0, stream>>>(out, mp0, mp1, mp2, mp3);
}